// Round 8
// baseline (2574.124 us; speedup 1.0000x reference)
//
#include <hip/hip_runtime.h>
#include <stdint.h>

// Sizes: x [16,1,512,512] f32 binary; weight [1024,512] f32; out [16,1,1024,529] f32.
// pot[b,o,t'] = sum_tau K(w[o,i],tau) * x[b,i,t'+15-tau] + 12.8
// K via cumsum^2 of its Delta^2 (<=2 adjacent pairs after moving the universal onset tap
// to an exact per-(b,t) histogram); pairs scattered at spike positions into 4 ramp-planes
// (v2 applied with +1 shift at cumsum time). WTA depression uniform -> per-batch counter.
// R8: R7 was VMEM-latency bound (tap loads stride 32KB/i -> L2-miss ~500cyc per i, 740
// cyc/wave-iter measured). Fix: o-major tap layout (32B/i streaming), packed spike dwords,
// counts x4, quad-unrolled depth-2-quad register prefetch. k_hist 32->256 blocks.

#define NB 16
#define NI 512
#define NT 512
#define NO 1024
#define TOUT 529
#define SCAP 96           // spike capacity per (b,i); max observed ~48
#define OTILE 4
#define NCELL 562         // e in [0,561) + dustbin @561
#define DUST 561u
#define THETA_F 25.6f
#define BIAS_T 12.8f

// ---------- P1: spike list (LDS-staged) + packed pair-words + counts ----------
__global__ __launch_bounds__(256) void k_spikes(const float* __restrict__ x,
                                                unsigned short* __restrict__ slist,
                                                unsigned int* __restrict__ spkw,
                                                unsigned int* __restrict__ counts) {
    __shared__ unsigned short sls[4][SCAP];
    int wq = threadIdx.x >> 6, lane = threadIdx.x & 63;
    int row = blockIdx.x * 4 + wq;                 // row = b*512 + i
    const float* xr = x + (size_t)row * NT;
    for (int j = lane; j < SCAP; j += 64) sls[wq][j] = 0xFFFFu;
    int base = 0;
    for (int kk = 0; kk < 8; ++kk) {
        int t = kk * 64 + lane;
        bool pred = xr[t] > 0.5f;
        unsigned long long mask = __ballot(pred);
        int pre = __popcll(mask & ((1ull << lane) - 1ull));
        int pos = base + pre;
        if (pred && pos < SCAP) sls[wq][pos] = (unsigned short)t;
        base += __popcll(mask);
    }
    __syncthreads();
    if (lane < SCAP / 2) {                         // full list for cold path
        unsigned v = (unsigned)sls[wq][2 * lane] | ((unsigned)sls[wq][2 * lane + 1] << 16);
        ((unsigned int*)(slist + (size_t)row * SCAP))[lane] = v;
    }
    if (lane < 32)                                 // packed (k, k+32) pair words
        spkw[(size_t)row * 32 + lane] = (unsigned)sls[wq][lane] | ((unsigned)sls[wq][lane + 32] << 16);
    if (lane == 0) counts[row] = (unsigned)min(base, SCAP);
}

// ---------- P1b: onset histogram, 256-block split + exact integer-f32 atomics ----------
__global__ __launch_bounds__(256) void k_hist(const float* __restrict__ x,
                                              float* __restrict__ hg) {
    int b = blockIdx.y, seg = blockIdx.z;          // 8 segs x 64 i
    int t = blockIdx.x * 256 + threadIdx.x;
    const float* xb = x + (size_t)b * NI * NT + (size_t)seg * 64 * NT + t;
    float s0 = 0.f, s1 = 0.f, s2 = 0.f, s3 = 0.f;
    for (int i = 0; i < 64; i += 4) {
        s0 += xb[(size_t)i * NT];       s1 += xb[(size_t)(i + 1) * NT];
        s2 += xb[(size_t)(i + 2) * NT]; s3 += xb[(size_t)(i + 3) * NT];
    }
    unsafeAtomicAdd(&hg[b * NT + t], (s0 + s1) + (s2 + s3));   // small ints: exact any order
}

// ---------- P2: per-(o,i) taps, o-MAJOR layout (streaming in k_scatter) ----------
// tap[((o*512+i)*2 + ramp)] = float4(v1, v2, pos_as_int_bits, 0). Empty pair: pos=2000
// (-> dustbin), v=0. Support is <= 2 adjacent runs after onset removal.
__global__ __launch_bounds__(256) void k_taps(const float* __restrict__ weight,
                                              float4* __restrict__ tap) {
    int p = blockIdx.x * 256 + threadIdx.x;        // 512*1024; i fast -> coalesced
    int o = p >> 9, i = p & 511;
    float w = weight[o * NI + i];
    float b15 = 1.5f * w;
    float vA1 = 0.f, vA2 = 0.f, vB1 = 0.f, vB2 = 0.f;
    int posA = 2000, posB = 2000, state = 0;
    float Km1 = 0.f, Km2 = 0.f;
    for (int tau = 0; tau <= 49; ++tau) {
        float K = 0.f;
        if (tau <= 47) {
            float f = (float)tau * 0.0625f;
            float g = b15 - (float)tau * 0.03125f;
            K = fmaxf(0.f, fminf(f, g));
        }
        float d = (K - Km1) - (Km1 - Km2);
        if (tau == 1) d -= 0.0625f;                // onset -> histogram
        if (d != 0.f) {
            if (state == 0)      { posA = tau; vA1 = d; state = 1; }
            else if (state == 1) { if (tau == posA + 1) { vA2 = d; state = 2; }
                                   else { posB = tau; vB1 = d; state = 3; } }
            else if (state == 2) { posB = tau; vB1 = d; state = 3; }
            else if (state == 3) { if (tau == posB + 1) { vB2 = d; state = 4; } }
        }
        Km2 = Km1; Km1 = K;
    }
    size_t base = 2 * ((size_t)o * NI + i);
    tap[base]     = make_float4(vA1, vA2, __int_as_float(posA), 0.f);
    tap[base + 1] = make_float4(vB1, vB2, __int_as_float(posB), 0.f);
}

// ---------- P3: wave-exclusive-row scatter + fused double cumsum^2 + pot write ----------
// Wave w owns acc row oo=w. Lane: k=lane>>1 spike slot, ramp=lane&1 pair slot.
// Quad-unrolled i-loop, double-buffered register prefetch (taps stream 32B/i o-major).
__global__ __launch_bounds__(256, 4) void k_scatter(const unsigned short* __restrict__ slist,
                                                    const unsigned int* __restrict__ spkw,
                                                    const unsigned int* __restrict__ counts,
                                                    const float4* __restrict__ tap,
                                                    const float* __restrict__ hg,
                                                    float* __restrict__ pot) {
    __shared__ float4 acc[OTILE * NCELL];          // 35,968 B
    __shared__ double pub[512];                    // 4,096 B
    const int o0 = blockIdx.x * OTILE;
    const int b  = blockIdx.y;
    const int tid = threadIdx.x;
    const int w = tid >> 6, lane = tid & 63;
    const int k = lane >> 1, ramp = lane & 1, ramp2 = ramp * 2;

    for (int idx = tid; idx < OTILE * NCELL; idx += 256) acc[idx] = make_float4(0.f, 0.f, 0.f, 0.f);
    __syncthreads();

    float* accw = (float*)(acc + w * NCELL);       // my wave's row
    const unsigned int* wrow = spkw + (size_t)(b * NI) * 32 + k;
    const float4* trow = tap + 2 * (size_t)(o0 + w) * NI + ramp;
    const uint4* crow = (const uint4*)(counts + b * NI);

    float4 tl[2][4]; unsigned wl[2][4]; uint4 cl[2];
#pragma unroll
    for (int st = 0; st < 2; ++st) {
#pragma unroll
        for (int m = 0; m < 4; ++m) {
            tl[st][m] = trow[(size_t)(st * 4 + m) * 2];
            wl[st][m] = wrow[(size_t)(st * 4 + m) * 32];
        }
        cl[st] = crow[st];
    }
    for (int iq = 0; iq < NI / 4; ++iq) {
        const int cur = iq & 1;
        float4 t0 = tl[cur][0], t1 = tl[cur][1], t2 = tl[cur][2], t3 = tl[cur][3];
        unsigned w0 = wl[cur][0], w1 = wl[cur][1], w2 = wl[cur][2], w3 = wl[cur][3];
        uint4 cc = cl[cur];
        if (iq + 2 < NI / 4) {                     // prefetch quad iq+2 (8 i ahead)
#pragma unroll
            for (int m = 0; m < 4; ++m) {
                tl[cur][m] = trow[(size_t)((iq + 2) * 4 + m) * 2];
                wl[cur][m] = wrow[(size_t)((iq + 2) * 4 + m) * 32];
            }
            cl[cur] = crow[iq + 2];
        }
#pragma unroll
        for (int m = 0; m < 4; ++m) {
            const float4 tp = (m == 0) ? t0 : (m == 1) ? t1 : (m == 2) ? t2 : t3;
            const unsigned wv = (m == 0) ? w0 : (m == 1) ? w1 : (m == 2) ? w2 : w3;
            const unsigned cnt = (m == 0) ? cc.x : (m == 1) ? cc.y : (m == 2) ? cc.z : cc.w;
            const int p = __float_as_int(tp.z);
            {
                unsigned e = min((unsigned)((int)(wv & 0xFFFFu) + p), DUST);
                float2* cell = (float2*)(accw + e * 4 + ramp2);
                float2 v = *cell; v.x += tp.x; v.y += tp.y; *cell = v;   // ds b64 RMW
            }
            if (cnt > 32u) {
                unsigned e = min((unsigned)((int)(wv >> 16) + p), DUST);
                float2* cell = (float2*)(accw + e * 4 + ramp2);
                float2 v = *cell; v.x += tp.x; v.y += tp.y; *cell = v;
            }
            if (cnt > 64u) {                       // cold: absent in this data
                const unsigned short* sr = slist + (size_t)(b * NI + iq * 4 + m) * SCAP;
                for (int kk = 64 + k; kk < (int)cnt; kk += 32) {
                    unsigned e = min((unsigned)((int)sr[kk] + p), DUST);
                    float2* cell = (float2*)(accw + e * 4 + ramp2);
                    float2 v = *cell; v.x += tp.x; v.y += tp.y; *cell = v;
                }
            }
        }
    }
    __syncthreads();

    // ---- cumsum^2 (double): thread (oo=w, q=lane) owns cells [9q, 9q+9) ----
    const int q = lane;
    const float4* rowQ = acc + w * NCELL;
    const float* hb = hg + b * NT;
    double dsv[9];
    double s1d = 0.0, s2d = 0.0;
#pragma unroll
    for (int r = 0; r < 9; ++r) {
        int e = q * 9 + r;
        double d = 0.0;
        if (e < 561) {
            float4 c = rowQ[e];
            d = (double)c.x + (double)c.z;
            if (e >= 1) {
                float4 cm = rowQ[e - 1];
                d += (double)cm.y + (double)cm.w;          // v2 planes: shifted +1
                if (e <= 512) d += 0.0625 * (double)hb[e - 1];
            }
        }
        dsv[r] = d; s1d += d; s2d += s1d;
    }
    pub[2 * tid] = s1d; pub[2 * tid + 1] = s2d;
    __syncthreads();
    if (tid < 4) {                                 // serial carry scan per o-row
        double c1 = 0.0, c2 = 0.0;
        for (int qq = 0; qq < 64; ++qq) {
            int j = (tid << 6) + qq;
            double S1 = pub[2 * j], S2 = pub[2 * j + 1];
            pub[2 * j] = c1; pub[2 * j + 1] = c2;
            c2 += 9.0 * c1 + S2;
            c1 += S1;
        }
    }
    __syncthreads();
    {
        const double C1 = pub[2 * tid], C2 = pub[2 * tid + 1];
        double a1 = 0.0, a2 = 0.0;
        float4* rowW = acc + w * NCELL;
#pragma unroll
        for (int r = 0; r < 9; ++r) {
            a1 += dsv[r]; a2 += a1;
            int e = q * 9 + r;
            if (e < 561) rowW[e].x = (float)(C2 + C1 * (double)(r + 1) + a2);
        }
    }
    __syncthreads();
    for (int oo = 0; oo < OTILE; ++oo)             // coalesced pot write (t fastest)
        for (int t = tid; t < TOUT; t += 256)
            pot[((size_t)(b * NO + o0 + oo)) * TOUT + t] = acc[oo * NCELL + t + 15].x + BIAS_T;
}

// ---------- P4: per-(b,t) argmax over 1024 neurons, first-index tie-break ----------
__global__ __launch_bounds__(256) void k_argmax(const float* __restrict__ pot,
                                                float* __restrict__ aval,
                                                unsigned short* __restrict__ aidx) {
    __shared__ float sv[4][64];
    __shared__ int   si[4][64];
    int b = blockIdx.y;
    int t0 = blockIdx.x * 64;
    int lane = threadIdx.x & 63, grp = threadIdx.x >> 6;
    int t = t0 + lane;
    bool valid = t < TOUT;
    float best = -1.f; int bidx = 0;
    if (valid) {
        for (int od = 0; od < 256; ++od) {         // ascending o + strict '>' => first max wins
            int o = grp * 256 + od;
            float v = pot[((size_t)(b * NO + o)) * TOUT + t];
            if (v > best) { best = v; bidx = o; }
        }
    }
    sv[grp][lane] = best; si[grp][lane] = bidx;
    __syncthreads();
    if (grp == 0 && valid) {
#pragma unroll
        for (int g = 1; g < 4; ++g) {
            float v = sv[g][lane];
            if (v > best) { best = v; bidx = si[g][lane]; }
        }
        aval[t * NB + b] = best;
        aidx[t * NB + b] = (unsigned short)bidx;
    }
}

// ---------- P5: serial refractory scan (depression uniform across neurons) ----------
__global__ __launch_bounds__(256) void k_wta(const float* __restrict__ aval,
                                             const unsigned short* __restrict__ aidx,
                                             float* __restrict__ out) {
    __shared__ float lv[TOUT * NB];
    __shared__ unsigned short li[TOUT * NB];
    for (int idx = threadIdx.x; idx < TOUT * NB; idx += 256) { lv[idx] = aval[idx]; li[idx] = aidx[idx]; }
    __syncthreads();
    int b = threadIdx.x;
    if (b < NB) {
        int r = 0;
        for (int t = 0; t < TOUT; ++t) {
            float v = lv[t * NB + b];
            if (r == 0 && v > THETA_F) {
                int n = (int)li[t * NB + b];
                out[((size_t)(b * NO + n)) * TOUT + t] = 1.0f;
                r = 48;
            }
            r = max(r - 1, 0);
        }
    }
}

extern "C" void kernel_launch(void* const* d_in, const int* in_sizes, int n_in,
                              void* d_out, int out_size, void* d_ws, size_t ws_size,
                              hipStream_t stream) {
    const float* x      = (const float*)d_in[0];   // [16,1,512,512]
    const float* weight = (const float*)d_in[1];   // [1024,512]
    float* out = (float*)d_out;                    // [16,1,1024,529]
    char* ws = (char*)d_ws;
    // ws layout (~19.5 MB)
    unsigned short* slist  = (unsigned short*)(ws);            // 8192*96*2     = 1,572,864
    unsigned int*   spkw   = (unsigned int*)(ws + 1572864);    // 8192*32*4     = 1,048,576
    unsigned int*   counts = (unsigned int*)(ws + 2621440);    // 8192*4        = 32,768
    float4*         tap    = (float4*)(ws + 2654208);          // 1024*512*2*16 = 16,777,216
    float*          hg     = (float*)(ws + 19431424);          // 16*512*4      = 32,768
    float*          aval   = (float*)(ws + 19464192);          // 529*16*4      = 33,856
    unsigned short* aidx   = (unsigned short*)(ws + 19498048); // 529*16*2      = 16,928

    k_spikes<<<2048, 256, 0, stream>>>(x, slist, spkw, counts);
    hipMemsetAsync(hg, 0, NB * NT * sizeof(float), stream);
    k_hist<<<dim3(2, NB, 8), 256, 0, stream>>>(x, hg);
    k_taps<<<2048, 256, 0, stream>>>(weight, tap);
    k_scatter<<<dim3(NO / OTILE, NB), 256, 0, stream>>>(slist, spkw, counts, tap, hg, out);
    k_argmax<<<dim3(9, 16), 256, 0, stream>>>(out, aval, aidx);
    hipMemsetAsync(d_out, 0, (size_t)out_size * sizeof(float), stream);   // clear pot
    k_wta<<<1, 256, 0, stream>>>(aval, aidx, out);                        // write spikes
}

// Round 9
// 503.257 us; speedup vs baseline: 5.1149x; 5.1149x over previous
//
#include <hip/hip_runtime.h>
#include <stdint.h>

// Sizes: x [16,1,512,512] f32 binary; weight [1024,512] f32; out [16,1,1024,529] f32.
// pot[b,o,t'] = sum_tau K(w[o,i],tau) * x[b,i,t'+15-tau] + 12.8
// K via cumsum^2 of its Delta^2 (<=2 adjacent pairs after moving the universal onset tap
// to an exact per-(b,t) histogram); pairs scattered at spike positions into 4 ramp-planes
// (v2 applied with +1 shift at cumsum time). WTA depression uniform -> per-batch counter.
// R9: R8's dynamic-indexed prefetch arrays spilled to scratch (10 GB HBM writes!).
// Same layout ideas, but statically-named scalar prefetch (registers only):
// o-major taps (32 B/i/wave contiguous), packed spike dwords, uint4 counts, quad unroll.

#define NB 16
#define NI 512
#define NT 512
#define NO 1024
#define TOUT 529
#define SCAP 96           // spike capacity per (b,i); max observed ~48
#define OTILE 4
#define NCELL 562         // e in [0,561) + dustbin @561
#define DUST 561u
#define THETA_F 25.6f
#define BIAS_T 12.8f

// ---------- P1: spike list (LDS-staged) + packed pair-words + counts ----------
__global__ __launch_bounds__(256) void k_spikes(const float* __restrict__ x,
                                                unsigned short* __restrict__ slist,
                                                unsigned int* __restrict__ spkw,
                                                unsigned int* __restrict__ counts) {
    __shared__ unsigned short sls[4][SCAP];
    int wq = threadIdx.x >> 6, lane = threadIdx.x & 63;
    int row = blockIdx.x * 4 + wq;                 // row = b*512 + i
    const float* xr = x + (size_t)row * NT;
    for (int j = lane; j < SCAP; j += 64) sls[wq][j] = 0xFFFFu;
    int base = 0;
    for (int kk = 0; kk < 8; ++kk) {
        int t = kk * 64 + lane;
        bool pred = xr[t] > 0.5f;
        unsigned long long mask = __ballot(pred);
        int pre = __popcll(mask & ((1ull << lane) - 1ull));
        int pos = base + pre;
        if (pred && pos < SCAP) sls[wq][pos] = (unsigned short)t;
        base += __popcll(mask);
    }
    __syncthreads();
    if (lane < SCAP / 2) {                         // full list for cold path
        unsigned v = (unsigned)sls[wq][2 * lane] | ((unsigned)sls[wq][2 * lane + 1] << 16);
        ((unsigned int*)(slist + (size_t)row * SCAP))[lane] = v;
    }
    if (lane < 32)                                 // packed (k, k+32) pair words
        spkw[(size_t)row * 32 + lane] = (unsigned)sls[wq][lane] | ((unsigned)sls[wq][lane + 32] << 16);
    if (lane == 0) counts[row] = (unsigned)min(base, SCAP);
}

// ---------- P1b: onset histogram, 256-block split + exact integer-f32 atomics ----------
__global__ __launch_bounds__(256) void k_hist(const float* __restrict__ x,
                                              float* __restrict__ hg) {
    int b = blockIdx.y, seg = blockIdx.z;          // 8 segs x 64 i
    int t = blockIdx.x * 256 + threadIdx.x;
    const float* xb = x + (size_t)b * NI * NT + (size_t)seg * 64 * NT + t;
    float s0 = 0.f, s1 = 0.f, s2 = 0.f, s3 = 0.f;
    for (int i = 0; i < 64; i += 4) {
        s0 += xb[(size_t)i * NT];       s1 += xb[(size_t)(i + 1) * NT];
        s2 += xb[(size_t)(i + 2) * NT]; s3 += xb[(size_t)(i + 3) * NT];
    }
    unsafeAtomicAdd(&hg[b * NT + t], (s0 + s1) + (s2 + s3));   // small ints: exact any order
}

// ---------- P2: per-(o,i) taps, o-MAJOR layout (streaming in k_scatter) ----------
// tap[((o*512+i)*2 + ramp)] = float4(v1, v2, pos_as_int_bits, 0). Empty pair: pos=2000
// (-> dustbin), v=0. Support is <= 2 adjacent runs after onset removal.
__global__ __launch_bounds__(256) void k_taps(const float* __restrict__ weight,
                                              float4* __restrict__ tap) {
    int p = blockIdx.x * 256 + threadIdx.x;        // 512*1024; i fast -> coalesced
    int o = p >> 9, i = p & 511;
    float w = weight[o * NI + i];
    float b15 = 1.5f * w;
    float vA1 = 0.f, vA2 = 0.f, vB1 = 0.f, vB2 = 0.f;
    int posA = 2000, posB = 2000, state = 0;
    float Km1 = 0.f, Km2 = 0.f;
    for (int tau = 0; tau <= 49; ++tau) {
        float K = 0.f;
        if (tau <= 47) {
            float f = (float)tau * 0.0625f;
            float g = b15 - (float)tau * 0.03125f;
            K = fmaxf(0.f, fminf(f, g));
        }
        float d = (K - Km1) - (Km1 - Km2);
        if (tau == 1) d -= 0.0625f;                // onset -> histogram
        if (d != 0.f) {
            if (state == 0)      { posA = tau; vA1 = d; state = 1; }
            else if (state == 1) { if (tau == posA + 1) { vA2 = d; state = 2; }
                                   else { posB = tau; vB1 = d; state = 3; } }
            else if (state == 2) { posB = tau; vB1 = d; state = 3; }
            else if (state == 3) { if (tau == posB + 1) { vB2 = d; state = 4; } }
        }
        Km2 = Km1; Km1 = K;
    }
    size_t base = 2 * ((size_t)o * NI + i);
    tap[base]     = make_float4(vA1, vA2, __int_as_float(posA), 0.f);
    tap[base + 1] = make_float4(vB1, vB2, __int_as_float(posB), 0.f);
}

// ---------- P3: wave-exclusive-row scatter + fused double cumsum^2 + pot write ----------
// Wave w owns acc row oo=w. Lane: k=lane>>1 spike slot, ramp=lane&1 pair slot.
// Statically-named quad prefetch (registers only -- R8's dynamic arrays spilled).
#define PROC(TP, WV, CNT, IDX)                                                        \
    {                                                                                 \
        const int p = __float_as_int((TP).z);                                         \
        {                                                                             \
            unsigned e = min((unsigned)((int)((WV) & 0xFFFFu) + p), DUST);            \
            float2* cell = (float2*)(accw + e * 4 + ramp2);                           \
            float2 v = *cell; v.x += (TP).x; v.y += (TP).y; *cell = v;                \
        }                                                                             \
        if ((CNT) > 32u) {                                                            \
            unsigned e = min((unsigned)((int)((WV) >> 16) + p), DUST);                \
            float2* cell = (float2*)(accw + e * 4 + ramp2);                           \
            float2 v = *cell; v.x += (TP).x; v.y += (TP).y; *cell = v;                \
        }                                                                             \
        if ((CNT) > 64u) {                                                            \
            const unsigned short* sr = slist + (size_t)(b * NI + (IDX)) * SCAP;       \
            for (int kk = 64 + k; kk < (int)(CNT); kk += 32) {                        \
                unsigned e = min((unsigned)((int)sr[kk] + p), DUST);                  \
                float2* cell = (float2*)(accw + e * 4 + ramp2);                       \
                float2 v = *cell; v.x += (TP).x; v.y += (TP).y; *cell = v;            \
            }                                                                         \
        }                                                                             \
    }

__global__ __launch_bounds__(256, 4) void k_scatter(const unsigned short* __restrict__ slist,
                                                    const unsigned int* __restrict__ spkw,
                                                    const unsigned int* __restrict__ counts,
                                                    const float4* __restrict__ tap,
                                                    const float* __restrict__ hg,
                                                    float* __restrict__ pot) {
    __shared__ float4 acc[OTILE * NCELL];          // 35,968 B
    __shared__ double pub[512];                    // 4,096 B
    const int o0 = blockIdx.x * OTILE;
    const int b  = blockIdx.y;
    const int tid = threadIdx.x;
    const int w = tid >> 6, lane = tid & 63;
    const int k = lane >> 1, ramp = lane & 1, ramp2 = ramp * 2;

    for (int idx = tid; idx < OTILE * NCELL; idx += 256) acc[idx] = make_float4(0.f, 0.f, 0.f, 0.f);
    __syncthreads();

    float* accw = (float*)(acc + w * NCELL);       // my wave's row
    const unsigned int* wrow = spkw + (size_t)(b * NI) * 32 + k;
    const float4* trow = tap + 2 * (size_t)(o0 + w) * NI + ramp;
    const uint4* crow = (const uint4*)(counts + b * NI);

    // prefetch quad 0 (all statically-named scalars -> registers)
    float4 ntA = trow[0], ntB = trow[2], ntC = trow[4], ntD = trow[6];
    unsigned nwA = wrow[0], nwB = wrow[32], nwC = wrow[64], nwD = wrow[96];
    uint4 ncc = crow[0];

    const int NIQ = NI / 4;
    for (int iq = 0; iq < NIQ; ++iq) {
        const float4 tA = ntA, tB = ntB, tC = ntC, tD = ntD;
        const unsigned wA = nwA, wB = nwB, wC = nwC, wD = nwD;
        const uint4 cc = ncc;
        if (iq + 1 < NIQ) {                        // prefetch next quad
            const float4* tb = trow + (size_t)(iq + 1) * 8;
            ntA = tb[0]; ntB = tb[2]; ntC = tb[4]; ntD = tb[6];
            const unsigned int* wb = wrow + (size_t)(iq + 1) * 128;
            nwA = wb[0]; nwB = wb[32]; nwC = wb[64]; nwD = wb[96];
            ncc = crow[iq + 1];
        }
        const int i0 = iq * 4;
        PROC(tA, wA, cc.x, i0)
        PROC(tB, wB, cc.y, i0 + 1)
        PROC(tC, wC, cc.z, i0 + 2)
        PROC(tD, wD, cc.w, i0 + 3)
    }
    __syncthreads();

    // ---- cumsum^2 (double): thread (oo=w, q=lane) owns cells [9q, 9q+9) ----
    const int q = lane;
    const float4* rowQ = acc + w * NCELL;
    const float* hb = hg + b * NT;
    double dsv[9];
    double s1d = 0.0, s2d = 0.0;
#pragma unroll
    for (int r = 0; r < 9; ++r) {
        int e = q * 9 + r;
        double d = 0.0;
        if (e < 561) {
            float4 c = rowQ[e];
            d = (double)c.x + (double)c.z;
            if (e >= 1) {
                float4 cm = rowQ[e - 1];
                d += (double)cm.y + (double)cm.w;          // v2 planes: shifted +1
                if (e <= 512) d += 0.0625 * (double)hb[e - 1];
            }
        }
        dsv[r] = d; s1d += d; s2d += s1d;
    }
    pub[2 * tid] = s1d; pub[2 * tid + 1] = s2d;
    __syncthreads();
    if (tid < 4) {                                 // serial carry scan per o-row
        double c1 = 0.0, c2 = 0.0;
        for (int qq = 0; qq < 64; ++qq) {
            int j = (tid << 6) + qq;
            double S1 = pub[2 * j], S2 = pub[2 * j + 1];
            pub[2 * j] = c1; pub[2 * j + 1] = c2;
            c2 += 9.0 * c1 + S2;
            c1 += S1;
        }
    }
    __syncthreads();
    {
        const double C1 = pub[2 * tid], C2 = pub[2 * tid + 1];
        double a1 = 0.0, a2 = 0.0;
        float4* rowW = acc + w * NCELL;
#pragma unroll
        for (int r = 0; r < 9; ++r) {
            a1 += dsv[r]; a2 += a1;
            int e = q * 9 + r;
            if (e < 561) rowW[e].x = (float)(C2 + C1 * (double)(r + 1) + a2);
        }
    }
    __syncthreads();
    for (int oo = 0; oo < OTILE; ++oo)             // coalesced pot write (t fastest)
        for (int t = tid; t < TOUT; t += 256)
            pot[((size_t)(b * NO + o0 + oo)) * TOUT + t] = acc[oo * NCELL + t + 15].x + BIAS_T;
}

// ---------- P4: per-(b,t) argmax over 1024 neurons, first-index tie-break ----------
__global__ __launch_bounds__(256) void k_argmax(const float* __restrict__ pot,
                                                float* __restrict__ aval,
                                                unsigned short* __restrict__ aidx) {
    __shared__ float sv[4][64];
    __shared__ int   si[4][64];
    int b = blockIdx.y;
    int t0 = blockIdx.x * 64;
    int lane = threadIdx.x & 63, grp = threadIdx.x >> 6;
    int t = t0 + lane;
    bool valid = t < TOUT;
    float best = -1.f; int bidx = 0;
    if (valid) {
        for (int od = 0; od < 256; ++od) {         // ascending o + strict '>' => first max wins
            int o = grp * 256 + od;
            float v = pot[((size_t)(b * NO + o)) * TOUT + t];
            if (v > best) { best = v; bidx = o; }
        }
    }
    sv[grp][lane] = best; si[grp][lane] = bidx;
    __syncthreads();
    if (grp == 0 && valid) {
#pragma unroll
        for (int g = 1; g < 4; ++g) {
            float v = sv[g][lane];
            if (v > best) { best = v; bidx = si[g][lane]; }
        }
        aval[t * NB + b] = best;
        aidx[t * NB + b] = (unsigned short)bidx;
    }
}

// ---------- P5: serial refractory scan (depression uniform across neurons) ----------
__global__ __launch_bounds__(256) void k_wta(const float* __restrict__ aval,
                                             const unsigned short* __restrict__ aidx,
                                             float* __restrict__ out) {
    __shared__ float lv[TOUT * NB];
    __shared__ unsigned short li[TOUT * NB];
    for (int idx = threadIdx.x; idx < TOUT * NB; idx += 256) { lv[idx] = aval[idx]; li[idx] = aidx[idx]; }
    __syncthreads();
    int b = threadIdx.x;
    if (b < NB) {
        int r = 0;
        for (int t = 0; t < TOUT; ++t) {
            float v = lv[t * NB + b];
            if (r == 0 && v > THETA_F) {
                int n = (int)li[t * NB + b];
                out[((size_t)(b * NO + n)) * TOUT + t] = 1.0f;
                r = 48;
            }
            r = max(r - 1, 0);
        }
    }
}

extern "C" void kernel_launch(void* const* d_in, const int* in_sizes, int n_in,
                              void* d_out, int out_size, void* d_ws, size_t ws_size,
                              hipStream_t stream) {
    const float* x      = (const float*)d_in[0];   // [16,1,512,512]
    const float* weight = (const float*)d_in[1];   // [1024,512]
    float* out = (float*)d_out;                    // [16,1,1024,529]
    char* ws = (char*)d_ws;
    // ws layout (~19.5 MB)
    unsigned short* slist  = (unsigned short*)(ws);            // 8192*96*2     = 1,572,864
    unsigned int*   spkw   = (unsigned int*)(ws + 1572864);    // 8192*32*4     = 1,048,576
    unsigned int*   counts = (unsigned int*)(ws + 2621440);    // 8192*4        = 32,768
    float4*         tap    = (float4*)(ws + 2654208);          // 1024*512*2*16 = 16,777,216
    float*          hg     = (float*)(ws + 19431424);          // 16*512*4      = 32,768
    float*          aval   = (float*)(ws + 19464192);          // 529*16*4      = 33,856
    unsigned short* aidx   = (unsigned short*)(ws + 19498048); // 529*16*2      = 16,928

    k_spikes<<<2048, 256, 0, stream>>>(x, slist, spkw, counts);
    hipMemsetAsync(hg, 0, NB * NT * sizeof(float), stream);
    k_hist<<<dim3(2, NB, 8), 256, 0, stream>>>(x, hg);
    k_taps<<<2048, 256, 0, stream>>>(weight, tap);
    k_scatter<<<dim3(NO / OTILE, NB), 256, 0, stream>>>(slist, spkw, counts, tap, hg, out);
    k_argmax<<<dim3(9, 16), 256, 0, stream>>>(out, aval, aidx);
    hipMemsetAsync(d_out, 0, (size_t)out_size * sizeof(float), stream);   // clear pot
    k_wta<<<1, 256, 0, stream>>>(aval, aidx, out);                        // write spikes
}